// Round 1
// baseline (175.274 us; speedup 1.0000x reference)
//
#include <hip/hip_runtime.h>

typedef unsigned short u16;
typedef unsigned int u32;
typedef short bf16x8 __attribute__((ext_vector_type(8)));
typedef float f32x4 __attribute__((ext_vector_type(4)));
typedef u16 u16x4 __attribute__((ext_vector_type(4)));

#define NAG 32
#define STATE 512
#define EMBED 64
#define TB 64   // samples per block; grid = 512 = 2 blocks/CU, one round

// d_ws bf16 layout (u16 element offsets).
// [0, 131072)      : WA  = concat(w1l1w, w2l1w, b1w, b2l1w) as [256][512]
// [131072, 262144) : WB  = w1l2w [2048][64]
// [262144, 266240) : WC  = w2l2w [64][64]
#define OFF_W1L1 0
#define OFF_W2L1 32768
#define OFF_B1W  65536
#define OFF_B2L1 98304
#define OFF_W1L2 131072
#define OFF_W2L2 262144
#define WS_TOTAL 266240

__device__ __forceinline__ float bf2f(u16 u) {
    u32 i = ((u32)u) << 16; float f;
    __builtin_memcpy(&f, &i, 4); return f;
}
__device__ __forceinline__ u16 f2bf(float f) {
    u32 i; __builtin_memcpy(&i, &f, 4);
    return (u16)((i + 0x8000u) >> 16);
}
__device__ __forceinline__ bf16x8 ld8(const u16* p) {
    return *reinterpret_cast<const bf16x8*>(p);
}
__device__ __forceinline__ bf16x8 cvt8(f32x4 a, f32x4 b) {
    bf16x8 r;
#pragma unroll
    for (int i = 0; i < 4; ++i) r[i]     = (short)f2bf(a[i]);
#pragma unroll
    for (int i = 0; i < 4; ++i) r[i + 4] = (short)f2bf(b[i]);
    return r;
}

__global__ __launch_bounds__(256) void cvt_weights(
    const float* __restrict__ w1l1w, const float* __restrict__ w2l1w,
    const float* __restrict__ b1w,   const float* __restrict__ b2l1w,
    const float* __restrict__ w1l2w, const float* __restrict__ w2l2w,
    u16* __restrict__ ws)
{
    int idx = blockIdx.x * 256 + threadIdx.x;
    const float* src; int off;
    if      (idx < OFF_W2L1)  { src = w1l1w; off = OFF_W1L1; }
    else if (idx < OFF_B1W)   { src = w2l1w; off = OFF_W2L1; }
    else if (idx < OFF_B2L1)  { src = b1w;   off = OFF_B1W;  }
    else if (idx < OFF_W1L2)  { src = b2l1w; off = OFF_B2L1; }
    else if (idx < OFF_W2L2)  { src = w1l2w; off = OFF_W1L2; }
    else if (idx < WS_TOTAL)  { src = w2l2w; off = OFF_W2L2; }
    else return;
    ws[idx] = f2bf(src[idx - off]);
}

// Decomposition (all weight fragments read DIRECTLY from global; weights are
// L2-resident and each fragment is consumed by exactly one wave -> staging
// them in LDS has zero reuse and was pure overhead):
//   Phase A: wave w computes Y[all 64 samples][features 64w..64w+64) -- no LDS,
//            no barriers, no waitcnt. B-frags stream from L2 (full-line use).
//   Phase B: wave w owns agents 8w..8w+8; partial hidden accum in registers,
//            one bf16 partial buffer + single cross-wave reduction.
//   Phase C/D: as before.
__global__ __launch_bounds__(256, 2) void qmix_kernel(
    const float* __restrict__ qs,    const float* __restrict__ st,
    const u16*  __restrict__ wsb,
    const float* __restrict__ w1l1b, const float* __restrict__ w1l2b,
    const float* __restrict__ w2l1b, const float* __restrict__ w2l2b,
    const float* __restrict__ b1b,   const float* __restrict__ b2l1b,
    const float* __restrict__ b2l2w, const float* __restrict__ b2l2b,
    float* __restrict__ out)
{
    __shared__ u16  y[TB][264];      // 33 KB: [0:64) h1 | [64:128) h2 | [128:192) b1v->hidden | [192:256) hb
    __shared__ u16  pbuf[4][TB][68]; // 34 KB: phase-B per-wave partials (bf16)
    __shared__ u16  qst[NAG][68];    // 4.25 KB: qs transposed bf16 [agent][sample]
    __shared__ u16  w1bs[2048];      // 4 KB w1l2b bf16
    __shared__ float qacc[TB];
    __shared__ float b2wv[64];
    // total ~77.5 KB -> 2 blocks/CU

    const int t    = threadIdx.x;
    const int wave = t >> 6, lane = t & 63;
    const int m = lane & 15, quad = lane >> 4;
    const int sbase = blockIdx.x * TB;

    // ---- prologue staging: qs->bf16 transposed, w1l2b->bf16, b2w ----
    if (t < 64) b2wv[t] = b2l2w[t];
    {
        const float* qp = qs + (size_t)sbase * NAG + t * 8;
        f32x4 q0 = *reinterpret_cast<const f32x4*>(qp);
        f32x4 q1 = *reinterpret_cast<const f32x4*>(qp + 4);
        const int s = t >> 2, a0 = (t & 3) * 8;
#pragma unroll
        for (int j = 0; j < 4; ++j) qst[a0 + j][s]     = f2bf(q0[j]);
#pragma unroll
        for (int j = 0; j < 4; ++j) qst[a0 + 4 + j][s] = f2bf(q1[j]);
        f32x4 w0 = *reinterpret_cast<const f32x4*>(w1l2b + t * 8);
        f32x4 w1 = *reinterpret_cast<const f32x4*>(w1l2b + t * 8 + 4);
        *reinterpret_cast<bf16x8*>(&w1bs[t * 8]) = cvt8(w0, w1);
    }

    // ---- Phase A: Y[0:64][wave*64 .. wave*64+64) = states @ WA^T (direct-global) ----
    const u16*   wArow = wsb + (size_t)(wave * 64) * STATE;
    const float* stb   = st + (size_t)sbase * STATE;

    f32x4 acc[4][4] = {};   // [sample-tile][out-tile]
    for (int ks = 0; ks < 8; ++ks) {       // K = 64 per iteration
        bf16x8 b[4][2];
#pragma unroll
        for (int ot = 0; ot < 4; ++ot) {
            const u16* wr = wArow + (size_t)(ot * 16 + m) * STATE + ks * 64 + quad * 8;
            b[ot][0] = ld8(wr);
            b[ot][1] = ld8(wr + 32);
        }
#pragma unroll
        for (int st2 = 0; st2 < 4; ++st2) {
            const float* ap = stb + (size_t)(st2 * 16 + m) * STATE + ks * 64 + quad * 8;
            f32x4 a0 = *reinterpret_cast<const f32x4*>(ap);
            f32x4 a1 = *reinterpret_cast<const f32x4*>(ap + 4);
            f32x4 a2 = *reinterpret_cast<const f32x4*>(ap + 32);
            f32x4 a3 = *reinterpret_cast<const f32x4*>(ap + 36);
            bf16x8 af0 = cvt8(a0, a1);
            bf16x8 af1 = cvt8(a2, a3);
#pragma unroll
            for (int ot = 0; ot < 4; ++ot)
                acc[st2][ot] = __builtin_amdgcn_mfma_f32_16x16x32_bf16(af0, b[ot][0], acc[st2][ot], 0, 0, 0);
#pragma unroll
            for (int ot = 0; ot < 4; ++ot)
                acc[st2][ot] = __builtin_amdgcn_mfma_f32_16x16x32_bf16(af1, b[ot][1], acc[st2][ot], 0, 0, 0);
        }
    }
    {   // epilogue: bias + (relu except b1v group), write y. wave-uniform group select.
        const float* barr = (wave == 0) ? w1l1b : (wave == 1) ? w2l1b : (wave == 2) ? b1b : b2l1b;
        const bool isrelu = (wave != 2);
        float wb[4];
#pragma unroll
        for (int ot = 0; ot < 4; ++ot) wb[ot] = barr[ot * 16 + m];
#pragma unroll
        for (int st2 = 0; st2 < 4; ++st2)
#pragma unroll
            for (int ot = 0; ot < 4; ++ot)
#pragma unroll
                for (int r = 0; r < 4; ++r) {
                    float v = acc[st2][ot][r] + wb[ot];
                    if (isrelu) v = fmaxf(v, 0.f);
                    y[st2 * 16 + quad * 4 + r][wave * 64 + ot * 16 + m] = f2bf(v);
                }
    }
    __syncthreads();   // B1: y complete (also covers prologue LDS)

    // ---- Phase B: wave w accumulates agents 8w..8w+8 over ALL 64 samples ----
    bf16x8 h1f[4][2];
#pragma unroll
    for (int st2 = 0; st2 < 4; ++st2) {
        h1f[st2][0] = *reinterpret_cast<const bf16x8*>(&y[st2 * 16 + m][quad * 8]);
        h1f[st2][1] = *reinterpret_cast<const bf16x8*>(&y[st2 * 16 + m][32 + quad * 8]);
    }

    f32x4 hacc[4][4] = {};   // [sample-tile][out-tile]
    for (int ag = 0; ag < 8; ++ag) {
        const int a = wave * 8 + ag;
        const u16* wp = wsb + OFF_W1L2 + (size_t)a * 64 * EMBED;
        bf16x8 b[4][2];
#pragma unroll
        for (int ot = 0; ot < 4; ++ot) {
            const u16* wr = wp + (size_t)(ot * 16 + m) * EMBED + quad * 8;
            b[ot][0] = ld8(wr);
            b[ot][1] = ld8(wr + 32);
        }
        float bias[4];
#pragma unroll
        for (int ot = 0; ot < 4; ++ot) bias[ot] = bf2f(w1bs[a * EMBED + ot * 16 + m]);
#pragma unroll
        for (int st2 = 0; st2 < 4; ++st2) {
            u16x4 qv = *reinterpret_cast<const u16x4*>(&qst[a][st2 * 16 + quad * 4]);
#pragma unroll
            for (int ot = 0; ot < 4; ++ot) {
                f32x4 p = {};
                p = __builtin_amdgcn_mfma_f32_16x16x32_bf16(h1f[st2][0], b[ot][0], p, 0, 0, 0);
                p = __builtin_amdgcn_mfma_f32_16x16x32_bf16(h1f[st2][1], b[ot][1], p, 0, 0, 0);
#pragma unroll
                for (int r = 0; r < 4; ++r)
                    hacc[st2][ot][r] += bf2f((u16)qv[r]) * fabsf(p[r] + bias[ot]);
            }
        }
    }
    // write per-wave partials (conflict-free: word = 8*quad + m/2 + 8*ot, all distinct)
#pragma unroll
    for (int st2 = 0; st2 < 4; ++st2)
#pragma unroll
        for (int ot = 0; ot < 4; ++ot)
#pragma unroll
            for (int r = 0; r < 4; ++r)
                pbuf[wave][st2 * 16 + quad * 4 + r][ot * 16 + m] = f2bf(hacc[st2][ot][r]);
    __syncthreads();   // B2: all partials in

    // ---- reduction: hidden = elu(sum_waves pbuf + b1v), written in place over b1v ----
    {
        const int s  = wave * 16 + (lane & 15);
        const int eb = (lane >> 4) * 16;
        float v[16];
#pragma unroll
        for (int j = 0; j < 16; ++j) v[j] = 0.f;
#pragma unroll
        for (int pw = 0; pw < 4; ++pw) {
#pragma unroll
            for (int c = 0; c < 4; ++c) {
                u16x4 x = *reinterpret_cast<const u16x4*>(&pbuf[pw][s][eb + c * 4]);
#pragma unroll
                for (int j = 0; j < 4; ++j) v[c * 4 + j] += bf2f((u16)x[j]);
            }
        }
        bf16x8 bv0 = *reinterpret_cast<const bf16x8*>(&y[s][128 + eb]);
        bf16x8 bv1 = *reinterpret_cast<const bf16x8*>(&y[s][128 + eb + 8]);
        bf16x8 o0, o1;
#pragma unroll
        for (int j = 0; j < 8; ++j) {
            float h0 = v[j] + bf2f((u16)bv0[j]);
            h0 = (h0 > 0.f) ? h0 : (__expf(h0) - 1.f);
            o0[j] = (short)f2bf(h0);
            float h1 = v[8 + j] + bf2f((u16)bv1[j]);
            h1 = (h1 > 0.f) ? h1 : (__expf(h1) - 1.f);
            o1[j] = (short)f2bf(h1);
        }
        *reinterpret_cast<bf16x8*>(&y[s][128 + eb])     = o0;
        *reinterpret_cast<bf16x8*>(&y[s][128 + eb + 8]) = o1;
    }
    __syncthreads();   // B3: hidden ready

    // ---- Phase C: w2 = |h2 @ W2l2^T + b|; q = sum_e hidden*w2 (wave-local, 16 samples) ----
    const int s0 = wave * 16;
    bf16x8 h2f0 = *reinterpret_cast<const bf16x8*>(&y[s0 + m][64 + quad * 8]);
    bf16x8 h2f1 = *reinterpret_cast<const bf16x8*>(&y[s0 + m][96 + quad * 8]);

    f32x4 qp = {};
#pragma unroll
    for (int tp = 0; tp < 4; ++tp) {
        const u16* wc = wsb + OFF_W2L2 + (size_t)(tp * 16 + m) * EMBED + quad * 8;
        bf16x8 b0 = ld8(wc);
        bf16x8 b1 = ld8(wc + 32);
        f32x4 p = {};
        p = __builtin_amdgcn_mfma_f32_16x16x32_bf16(h2f0, b0, p, 0, 0, 0);
        p = __builtin_amdgcn_mfma_f32_16x16x32_bf16(h2f1, b1, p, 0, 0, 0);
        const float bias = w2l2b[tp * 16 + m];
#pragma unroll
        for (int r = 0; r < 4; ++r)
            qp[r] += bf2f(y[s0 + quad * 4 + r][128 + tp * 16 + m]) * fabsf(p[r] + bias);
    }
#pragma unroll
    for (int off = 1; off < 16; off <<= 1) {
#pragma unroll
        for (int r = 0; r < 4; ++r) qp[r] += __shfl_xor(qp[r], off, 64);
    }
    if (m == 0) {
#pragma unroll
        for (int r = 0; r < 4; ++r) qacc[s0 + quad * 4 + r] = qp[r];
    }
    __syncthreads();   // B4: qacc ready

    // ---- Phase D: b2 + final sum (LDS-only) ----
    if (t < TB) {
        float q = qacc[t] + b2l2b[0];
        float acc2 = 0.f;
#pragma unroll
        for (int kk = 0; kk < 8; ++kk) {
            bf16x8 hv = *reinterpret_cast<const bf16x8*>(&y[t][192 + kk * 8]);
#pragma unroll
            for (int j = 0; j < 8; ++j)
                acc2 += bf2f((u16)hv[j]) * b2wv[kk * 8 + j];
        }
        out[sbase + t] = q + acc2;
    }
}

extern "C" void kernel_launch(void* const* d_in, const int* in_sizes, int n_in,
                              void* d_out, int out_size, void* d_ws, size_t ws_size,
                              hipStream_t stream)
{
    const float* qs    = (const float*)d_in[0];
    const float* st    = (const float*)d_in[1];
    const float* w1l1w = (const float*)d_in[2];
    const float* w1l1b = (const float*)d_in[3];
    const float* w1l2w = (const float*)d_in[4];
    const float* w1l2b = (const float*)d_in[5];
    const float* w2l1w = (const float*)d_in[6];
    const float* w2l1b = (const float*)d_in[7];
    const float* w2l2w = (const float*)d_in[8];
    const float* w2l2b = (const float*)d_in[9];
    const float* b1w   = (const float*)d_in[10];
    const float* b1b   = (const float*)d_in[11];
    const float* b2l1w = (const float*)d_in[12];
    const float* b2l1b = (const float*)d_in[13];
    const float* b2l2w = (const float*)d_in[14];
    const float* b2l2b = (const float*)d_in[15];

    u16* wsb = (u16*)d_ws;

    cvt_weights<<<(WS_TOTAL + 255) / 256, 256, 0, stream>>>(
        w1l1w, w2l1w, b1w, b2l1w, w1l2w, w2l2w, wsb);

    int B = in_sizes[0] / NAG;        // 32768
    int grid = B / TB;                // 512 = 2 blocks/CU, single round
    qmix_kernel<<<grid, 256, 0, stream>>>(
        qs, st, wsb,
        w1l1b, w1l2b, w2l1b, w2l2b, b1b, b2l1b, b2l2w, b2l2b,
        (float*)d_out);
}

// Round 2
// 157.261 us; speedup vs baseline: 1.1145x; 1.1145x over previous
//
#include <hip/hip_runtime.h>

typedef unsigned short u16;
typedef unsigned int u32;
typedef short bf16x8 __attribute__((ext_vector_type(8)));
typedef float f32x4 __attribute__((ext_vector_type(4)));
typedef u16 u16x4 __attribute__((ext_vector_type(4)));

#define NAG 32
#define STATE 512
#define EMBED 64
#define TB 64   // samples per block; grid = 512 = 2 blocks/CU, one round

// d_ws bf16 layout (u16 element offsets).
#define OFF_W1L1 0
#define OFF_W2L1 32768
#define OFF_B1W  65536
#define OFF_B2L1 98304
#define OFF_W1L2 131072
#define OFF_W2L2 262144
#define WS_TOTAL 266240

// smem layout (u16 offsets). Total 30592 u16 = 59.75 KB -> 2 blocks/CU.
#define Y_STR    200          // y[64][200]: [0,64) h1 | [64,128) h2 | [128,192) b1v->hidden
#define SB_OFF   12800        // sb[2][64][72] bf16 state K-slices (padded rows)
#define SB_STR   72
#define SB_BUF   (64 * 72)
#define W1BS_OFF 22016        // w1l2b bf16 [2048]
#define QST_OFF  24064        // qs^T bf16 [32][68]
#define QST_STR  68
#define PBUF_OFF 12800        // phase-B partials [4][64][68] — overlays sb/w1bs/qst (dead)
#define PBUF_STR 68
#define PBUF_WV  (64 * 68)
#define QACC_OFF  30208       // f32[64]
#define QACC2_OFF 30336       // f32[64]
#define B2WV_OFF  30464       // f32[64]
#define SMEM_U16  30592

__device__ __forceinline__ float bf2f(u16 u) {
    u32 i = ((u32)u) << 16; float f;
    __builtin_memcpy(&f, &i, 4); return f;
}
__device__ __forceinline__ u16 f2bf(float f) {
    u32 i; __builtin_memcpy(&i, &f, 4);
    return (u16)((i + 0x8000u) >> 16);
}
__device__ __forceinline__ bf16x8 ld8(const u16* p) {
    return *reinterpret_cast<const bf16x8*>(p);
}
__device__ __forceinline__ bf16x8 cvt8(f32x4 a, f32x4 b) {
    bf16x8 r;
#pragma unroll
    for (int i = 0; i < 4; ++i) r[i]     = (short)f2bf(a[i]);
#pragma unroll
    for (int i = 0; i < 4; ++i) r[i + 4] = (short)f2bf(b[i]);
    return r;
}

__global__ __launch_bounds__(256) void cvt_weights(
    const float* __restrict__ w1l1w, const float* __restrict__ w2l1w,
    const float* __restrict__ b1w,   const float* __restrict__ b2l1w,
    const float* __restrict__ w1l2w, const float* __restrict__ w2l2w,
    u16* __restrict__ ws)
{
    int idx = blockIdx.x * 256 + threadIdx.x;
    const float* src; int off;
    if      (idx < OFF_W2L1)  { src = w1l1w; off = OFF_W1L1; }
    else if (idx < OFF_B1W)   { src = w2l1w; off = OFF_W2L1; }
    else if (idx < OFF_B2L1)  { src = b1w;   off = OFF_B1W;  }
    else if (idx < OFF_W1L2)  { src = b2l1w; off = OFF_B2L1; }
    else if (idx < OFF_W2L2)  { src = w1l2w; off = OFF_W1L2; }
    else if (idx < WS_TOTAL)  { src = w2l2w; off = OFF_W2L2; }
    else return;
    ws[idx] = f2bf(src[idx - off]);
}

// Work split (zero weight-fragment redundancy; states staged ONCE per block):
//  Phase A: wave w owns features [64w,64w+64) x all 64 samples. Weights direct
//           from global (L2-resident, reg-prefetched ping-pong). States staged
//           cooperatively in LDS bf16, double-buffered K=64 slices, coalesced.
//  Wave 3's output (hb) is dotted with b2l2w immediately (shfl reduce) -> qacc2.
//  Phase B: wave w owns agents [8w,8w+8) x all samples; partial hidden in regs,
//           one bf16 partial buffer + single cross-wave reduction.
//  Phase C: per-wave 16 samples: w2 = |h2 @ W2l2^T + b|, dot with hidden.
//  Phase D: out = qacc + qacc2 + b2l2b.
__global__ __launch_bounds__(256, 2) void qmix_kernel(
    const float* __restrict__ qs,    const float* __restrict__ st,
    const u16*  __restrict__ wsb,
    const float* __restrict__ w1l1b, const float* __restrict__ w1l2b,
    const float* __restrict__ w2l1b, const float* __restrict__ w2l2b,
    const float* __restrict__ b1b,   const float* __restrict__ b2l1b,
    const float* __restrict__ b2l2w, const float* __restrict__ b2l2b,
    float* __restrict__ out)
{
    __shared__ u16 smem[SMEM_U16];
    float* qaccF  = (float*)(smem + QACC_OFF);
    float* qacc2F = (float*)(smem + QACC2_OFF);
    float* b2wvF  = (float*)(smem + B2WV_OFF);

    const int t    = threadIdx.x;
    const int wave = t >> 6, lane = t & 63;
    const int m = lane & 15, quad = lane >> 4;
    const int sbase = blockIdx.x * TB;

    // ---- prologue staging ----
    if (t < 64) b2wvF[t] = b2l2w[t];
    {   // qs -> bf16 transposed [agent][sample]
        const float* qp = qs + (size_t)sbase * NAG + t * 8;
        f32x4 q0 = *reinterpret_cast<const f32x4*>(qp);
        f32x4 q1 = *reinterpret_cast<const f32x4*>(qp + 4);
        const int s = t >> 2, a0 = (t & 3) * 8;
#pragma unroll
        for (int j = 0; j < 4; ++j) smem[QST_OFF + (a0 + j) * QST_STR + s]     = f2bf(q0[j]);
#pragma unroll
        for (int j = 0; j < 4; ++j) smem[QST_OFF + (a0 + 4 + j) * QST_STR + s] = f2bf(q1[j]);
        // w1l2b -> bf16
        f32x4 w0 = *reinterpret_cast<const f32x4*>(w1l2b + t * 8);
        f32x4 w1 = *reinterpret_cast<const f32x4*>(w1l2b + t * 8 + 4);
        *reinterpret_cast<bf16x8*>(&smem[W1BS_OFF + t * 8]) = cvt8(w0, w1);
    }

    // states staging helpers: thread owns (sample t>>3, chunk t&7) and (+32, same chunk)
    const int ss1 = t >> 3, c8 = t & 7;
    const float* stb = st + (size_t)sbase * STATE;

    {   // stage slice 0 into sb[0]
        const float* g1 = stb + (size_t)ss1 * STATE + c8 * 8;
        const float* g2 = g1 + (size_t)32 * STATE;
        f32x4 a0 = *reinterpret_cast<const f32x4*>(g1);
        f32x4 a1 = *reinterpret_cast<const f32x4*>(g1 + 4);
        f32x4 a2 = *reinterpret_cast<const f32x4*>(g2);
        f32x4 a3 = *reinterpret_cast<const f32x4*>(g2 + 4);
        u16* dst = smem + SB_OFF;
        *reinterpret_cast<bf16x8*>(&dst[ss1 * SB_STR + c8 * 8])        = cvt8(a0, a1);
        *reinterpret_cast<bf16x8*>(&dst[(ss1 + 32) * SB_STR + c8 * 8]) = cvt8(a2, a3);
    }

    // ---- Phase A: acc[st2][ot] over K=512 in 8 slices; weights reg-prefetched ----
    const u16* wAw = wsb + (size_t)(wave * 64) * STATE;
    bf16x8 bfr[2][4][2];
#pragma unroll
    for (int ot = 0; ot < 4; ++ot) {
        const u16* wr = wAw + (size_t)(ot * 16 + m) * STATE + quad * 8;
        bfr[0][ot][0] = ld8(wr);
        bfr[0][ot][1] = ld8(wr + 32);
    }
    __syncthreads();   // sb[0] + prologue visible

    f32x4 acc[4][4] = {};
#pragma unroll
    for (int ks = 0; ks < 8; ++ks) {
        // issue next-slice state loads (to regs) and weight gathers (ping-pong)
        f32x4 sa0 = {}, sa1 = {}, sa2 = {}, sa3 = {};
        if (ks < 7) {
            const float* g1 = stb + (size_t)ss1 * STATE + (ks + 1) * 64 + c8 * 8;
            const float* g2 = g1 + (size_t)32 * STATE;
            sa0 = *reinterpret_cast<const f32x4*>(g1);
            sa1 = *reinterpret_cast<const f32x4*>(g1 + 4);
            sa2 = *reinterpret_cast<const f32x4*>(g2);
            sa3 = *reinterpret_cast<const f32x4*>(g2 + 4);
#pragma unroll
            for (int ot = 0; ot < 4; ++ot) {
                const u16* wr = wAw + (size_t)(ot * 16 + m) * STATE + (ks + 1) * 64 + quad * 8;
                bfr[(ks + 1) & 1][ot][0] = ld8(wr);
                bfr[(ks + 1) & 1][ot][1] = ld8(wr + 32);
            }
        }
        // compute slice ks
        const u16* sbc = smem + SB_OFF + (ks & 1) * SB_BUF;
#pragma unroll
        for (int st2 = 0; st2 < 4; ++st2) {
            const int row = st2 * 16 + m;
            bf16x8 af0 = ld8(&sbc[row * SB_STR + quad * 8]);
            bf16x8 af1 = ld8(&sbc[row * SB_STR + (quad + 4) * 8]);
#pragma unroll
            for (int ot = 0; ot < 4; ++ot)
                acc[st2][ot] = __builtin_amdgcn_mfma_f32_16x16x32_bf16(af0, bfr[ks & 1][ot][0], acc[st2][ot], 0, 0, 0);
#pragma unroll
            for (int ot = 0; ot < 4; ++ot)
                acc[st2][ot] = __builtin_amdgcn_mfma_f32_16x16x32_bf16(af1, bfr[ks & 1][ot][1], acc[st2][ot], 0, 0, 0);
        }
        // write next slice (waits on sa loads; latency covered by compute above)
        if (ks < 7) {
            u16* dst = smem + SB_OFF + ((ks + 1) & 1) * SB_BUF;
            *reinterpret_cast<bf16x8*>(&dst[ss1 * SB_STR + c8 * 8])        = cvt8(sa0, sa1);
            *reinterpret_cast<bf16x8*>(&dst[(ss1 + 32) * SB_STR + c8 * 8]) = cvt8(sa2, sa3);
        }
        __syncthreads();
    }

    // ---- Phase A epilogue ----
    if (wave != 3) {
        const float* barr = (wave == 0) ? w1l1b : (wave == 1) ? w2l1b : b1b;
        const bool isrelu = (wave != 2);
        float wb[4];
#pragma unroll
        for (int ot = 0; ot < 4; ++ot) wb[ot] = barr[ot * 16 + m];
#pragma unroll
        for (int st2 = 0; st2 < 4; ++st2)
#pragma unroll
            for (int ot = 0; ot < 4; ++ot)
#pragma unroll
                for (int r = 0; r < 4; ++r) {
                    float v = acc[st2][ot][r] + wb[ot];
                    if (isrelu) v = fmaxf(v, 0.f);
                    smem[(st2 * 16 + quad * 4 + r) * Y_STR + wave * 64 + ot * 16 + m] = f2bf(v);
                }
    } else {
        // hb = relu(states @ b2l1 + b); immediately dot with b2l2w -> qacc2
        float wb[4], bw[4];
#pragma unroll
        for (int ot = 0; ot < 4; ++ot) wb[ot] = b2l1b[ot * 16 + m];
#pragma unroll
        for (int ot = 0; ot < 4; ++ot) bw[ot] = b2wvF[ot * 16 + m];
#pragma unroll
        for (int st2 = 0; st2 < 4; ++st2)
#pragma unroll
            for (int r = 0; r < 4; ++r) {
                float pd = 0.f;
#pragma unroll
                for (int ot = 0; ot < 4; ++ot)
                    pd += fmaxf(acc[st2][ot][r] + wb[ot], 0.f) * bw[ot];
#pragma unroll
                for (int off = 1; off < 16; off <<= 1) pd += __shfl_xor(pd, off, 64);
                if (m == 0) qacc2F[st2 * 16 + quad * 4 + r] = pd;
            }
    }
    __syncthreads();   // y + qacc2 ready

    // ---- Phase B: wave w accumulates agents 8w..8w+8 over all 64 samples ----
    bf16x8 h1f[4][2];
#pragma unroll
    for (int st2 = 0; st2 < 4; ++st2) {
        h1f[st2][0] = ld8(&smem[(st2 * 16 + m) * Y_STR + quad * 8]);
        h1f[st2][1] = ld8(&smem[(st2 * 16 + m) * Y_STR + 32 + quad * 8]);
    }

    const u16* wB = wsb + OFF_W1L2 + (size_t)(wave * 8) * 64 * EMBED;
    bf16x8 bb[2][4][2];
#pragma unroll
    for (int ot = 0; ot < 4; ++ot) {
        const u16* wr = wB + (size_t)(ot * 16 + m) * EMBED + quad * 8;
        bb[0][ot][0] = ld8(wr);
        bb[0][ot][1] = ld8(wr + 32);
    }

    f32x4 hacc[4][4] = {};
#pragma unroll
    for (int ag = 0; ag < 8; ++ag) {
        if (ag < 7) {
#pragma unroll
            for (int ot = 0; ot < 4; ++ot) {
                const u16* wr = wB + (size_t)((ag + 1) * 64 + ot * 16 + m) * EMBED + quad * 8;
                bb[(ag + 1) & 1][ot][0] = ld8(wr);
                bb[(ag + 1) & 1][ot][1] = ld8(wr + 32);
            }
        }
        const int a = wave * 8 + ag;
        float bias[4];
#pragma unroll
        for (int ot = 0; ot < 4; ++ot) bias[ot] = bf2f(smem[W1BS_OFF + a * EMBED + ot * 16 + m]);
#pragma unroll
        for (int st2 = 0; st2 < 4; ++st2) {
            u16x4 qv = *reinterpret_cast<const u16x4*>(&smem[QST_OFF + a * QST_STR + st2 * 16 + quad * 4]);
#pragma unroll
            for (int ot = 0; ot < 4; ++ot) {
                f32x4 p = {};
                p = __builtin_amdgcn_mfma_f32_16x16x32_bf16(h1f[st2][0], bb[ag & 1][ot][0], p, 0, 0, 0);
                p = __builtin_amdgcn_mfma_f32_16x16x32_bf16(h1f[st2][1], bb[ag & 1][ot][1], p, 0, 0, 0);
#pragma unroll
                for (int r = 0; r < 4; ++r)
                    hacc[st2][ot][r] += bf2f((u16)qv[r]) * fabsf(p[r] + bias[ot]);
            }
        }
    }
    __syncthreads();   // all waves done with w1bs/qst/sb -> safe to overlay pbuf

    // per-wave partials (stride-68 rows: conflict-free scalar writes)
#pragma unroll
    for (int st2 = 0; st2 < 4; ++st2)
#pragma unroll
        for (int ot = 0; ot < 4; ++ot)
#pragma unroll
            for (int r = 0; r < 4; ++r)
                smem[PBUF_OFF + wave * PBUF_WV + (st2 * 16 + quad * 4 + r) * PBUF_STR + ot * 16 + m]
                    = f2bf(hacc[st2][ot][r]);
    __syncthreads();   // partials in

    // ---- reduction: hidden = elu(sum_waves pbuf + b1v), in place over b1v ----
    {
        const int s  = wave * 16 + (lane & 15);
        const int eb = (lane >> 4) * 16;
        float v[16];
#pragma unroll
        for (int j = 0; j < 16; ++j) v[j] = 0.f;
#pragma unroll
        for (int pw = 0; pw < 4; ++pw) {
#pragma unroll
            for (int c = 0; c < 4; ++c) {
                u16x4 x = *reinterpret_cast<const u16x4*>(
                    &smem[PBUF_OFF + pw * PBUF_WV + s * PBUF_STR + eb + c * 4]);
#pragma unroll
                for (int j = 0; j < 4; ++j) v[c * 4 + j] += bf2f((u16)x[j]);
            }
        }
        bf16x8 bv0 = ld8(&smem[s * Y_STR + 128 + eb]);
        bf16x8 bv1 = ld8(&smem[s * Y_STR + 128 + eb + 8]);
        bf16x8 o0, o1;
#pragma unroll
        for (int j = 0; j < 8; ++j) {
            float h0 = v[j] + bf2f((u16)bv0[j]);
            h0 = (h0 > 0.f) ? h0 : (__expf(h0) - 1.f);
            o0[j] = (short)f2bf(h0);
            float h1 = v[8 + j] + bf2f((u16)bv1[j]);
            h1 = (h1 > 0.f) ? h1 : (__expf(h1) - 1.f);
            o1[j] = (short)f2bf(h1);
        }
        *reinterpret_cast<bf16x8*>(&smem[s * Y_STR + 128 + eb])     = o0;
        *reinterpret_cast<bf16x8*>(&smem[s * Y_STR + 128 + eb + 8]) = o1;
    }
    __syncthreads();   // hidden ready

    // ---- Phase C: w2 = |h2 @ W2l2^T + b|; q = sum_e hidden*w2 (16 samples/wave) ----
    const int s0 = wave * 16;
    bf16x8 h2f0 = ld8(&smem[(s0 + m) * Y_STR + 64 + quad * 8]);
    bf16x8 h2f1 = ld8(&smem[(s0 + m) * Y_STR + 96 + quad * 8]);

    f32x4 qp = {};
#pragma unroll
    for (int tp = 0; tp < 4; ++tp) {
        const u16* wc = wsb + OFF_W2L2 + (size_t)(tp * 16 + m) * EMBED + quad * 8;
        bf16x8 c0 = ld8(wc);
        bf16x8 c1 = ld8(wc + 32);
        f32x4 p = {};
        p = __builtin_amdgcn_mfma_f32_16x16x32_bf16(h2f0, c0, p, 0, 0, 0);
        p = __builtin_amdgcn_mfma_f32_16x16x32_bf16(h2f1, c1, p, 0, 0, 0);
        const float bias = w2l2b[tp * 16 + m];
#pragma unroll
        for (int r = 0; r < 4; ++r)
            qp[r] += bf2f(smem[(s0 + quad * 4 + r) * Y_STR + 128 + tp * 16 + m]) * fabsf(p[r] + bias);
    }
#pragma unroll
    for (int off = 1; off < 16; off <<= 1) {
#pragma unroll
        for (int r = 0; r < 4; ++r) qp[r] += __shfl_xor(qp[r], off, 64);
    }
    if (m == 0) {
#pragma unroll
        for (int r = 0; r < 4; ++r) qaccF[s0 + quad * 4 + r] = qp[r];
    }
    __syncthreads();   // qacc ready

    // ---- Phase D ----
    if (t < TB) out[sbase + t] = qaccF[t] + qacc2F[t] + b2l2b[0];
}

extern "C" void kernel_launch(void* const* d_in, const int* in_sizes, int n_in,
                              void* d_out, int out_size, void* d_ws, size_t ws_size,
                              hipStream_t stream)
{
    const float* qs    = (const float*)d_in[0];
    const float* st    = (const float*)d_in[1];
    const float* w1l1w = (const float*)d_in[2];
    const float* w1l1b = (const float*)d_in[3];
    const float* w1l2w = (const float*)d_in[4];
    const float* w1l2b = (const float*)d_in[5];
    const float* w2l1w = (const float*)d_in[6];
    const float* w2l1b = (const float*)d_in[7];
    const float* w2l2w = (const float*)d_in[8];
    const float* w2l2b = (const float*)d_in[9];
    const float* b1w   = (const float*)d_in[10];
    const float* b1b   = (const float*)d_in[11];
    const float* b2l1w = (const float*)d_in[12];
    const float* b2l1b = (const float*)d_in[13];
    const float* b2l2w = (const float*)d_in[14];
    const float* b2l2b = (const float*)d_in[15];

    u16* wsb = (u16*)d_ws;

    cvt_weights<<<(WS_TOTAL + 255) / 256, 256, 0, stream>>>(
        w1l1w, w2l1w, b1w, b2l1w, w1l2w, w2l2w, wsb);

    int B = in_sizes[0] / NAG;        // 32768
    int grid = B / TB;                // 512 = 2 blocks/CU, single round
    qmix_kernel<<<grid, 256, 0, stream>>>(
        qs, st, wsb,
        w1l1b, w1l2b, w2l1b, w2l2b, b1b, b2l1b, b2l2w, b2l2b,
        (float*)d_out);
}